// Round 1
// baseline (71.812 us; speedup 1.0000x reference)
//
#include <hip/hip_runtime.h>
#include <stdint.h>

// Tropical (max-plus) matmul: Y[b][j] = max_k X[b][k] + W[j][k]
// M=512, N=1024, K=1024, fp32 in/out.
//
// Exact candidate pruning: with D >= max_j (max_k W[j,k] - min_k W[j,k]),
// any k with X[b,k] <= Xmax_b - D loses to k* = argmax X[b,:] for every j.
// Global spread D'' = max(W) - min(W) bounds that (still exact; ~1.4
// candidates/row at W = randn*0.02). CAP overflow -> exact full-scan
// fallback keeps the kernel correct for ANY input.
//
// R17 (vs R16): kill the 4MB Wt transpose entirely. K2 touched only ~0.3%
// of Wt (~1.4 candidate columns/row), so the transpose was 8MB of HBM
// traffic + LDS round-trip feeding almost nothing. Now:
//   K1: 256 blocks, pure streaming min/max scan of W (4MB read, 2KB write).
//   K2: computes Xmax_b in-block (X row is loaded anyway), gathers the few
//       candidate columns directly from row-major W (scattered 4B reads,
//       L3-resident after K1's stream -> ~64KB cache traffic per candidate
//       per block, negligible volume).
// K1 grid 768 -> 256; kernel-side HBM bytes ~16MB -> ~8MB.

#define M_DIM 512
#define N_DIM 1024
#define K_DIM 1024
#define CAP   256
#define NSTAT 256

// ws layout: tmax 1KB | tmin 1KB
#define OFF_TMAX 0
#define OFF_TMIN 1024u

// ---- K1: per-block min/max of a contiguous 16KB chunk of W ----
__global__ __launch_bounds__(256)
void wstats(const float* __restrict__ W, float* __restrict__ tmax,
            float* __restrict__ tmin) {
    __shared__ float smx[4];
    __shared__ float smn[4];
    const int tid = threadIdx.x;
    const int bx = blockIdx.x;
    const float4* W4 = (const float4*)W;

    float mx = -3.0e38f, mn = 3.0e38f;
#pragma unroll
    for (int t = 0; t < 4; t++) {
        float4 f = W4[(size_t)bx * 1024 + t * 256 + tid];
        mx = fmaxf(mx, fmaxf(fmaxf(f.x, f.y), fmaxf(f.z, f.w)));
        mn = fminf(mn, fminf(fminf(f.x, f.y), fminf(f.z, f.w)));
    }
#pragma unroll
    for (int off = 32; off > 0; off >>= 1) {
        mx = fmaxf(mx, __shfl_down(mx, off, 64));
        mn = fminf(mn, __shfl_down(mn, off, 64));
    }
    if ((tid & 63) == 0) { smx[tid >> 6] = mx; smn[tid >> 6] = mn; }
    __syncthreads();
    if (tid == 0) {
        tmax[bx] = fmaxf(fmaxf(smx[0], smx[1]), fmaxf(smx[2], smx[3]));
        tmin[bx] = fminf(fminf(smn[0], smn[1]), fminf(smn[2], smn[3]));
    }
}

// ---- K2: D (wave-0 butterfly), Xmax_b (in-block), candidates, column gather ----
__global__ __launch_bounds__(256)
void emit_pruned(const float* __restrict__ X, const float* __restrict__ W,
                 const float* __restrict__ tmax, const float* __restrict__ tmin,
                 float* __restrict__ out) {
    __shared__ float sD;
    __shared__ float sXm[4];
    __shared__ float sX[K_DIM];      // fallback only (written unconditionally, cheap)
    __shared__ float sval[CAP];
    __shared__ int   sidx[CAP];
    __shared__ int   scnt;

    const int tid = threadIdx.x;
    const int b = blockIdx.x;

    // --- D'' = max(W) - min(W) from 256 block-stat pairs (2KB), wave-0 butterfly ---
    if (tid < 64) {
        float4 a = ((const float4*)tmax)[tid];
        float4 i = ((const float4*)tmin)[tid];
        float mx = fmaxf(fmaxf(a.x, a.y), fmaxf(a.z, a.w));
        float mn = fminf(fminf(i.x, i.y), fminf(i.z, i.w));
#pragma unroll
        for (int off = 32; off > 0; off >>= 1) {
            mx = fmaxf(mx, __shfl_down(mx, off, 64));
            mn = fminf(mn, __shfl_down(mn, off, 64));
        }
        if (tid == 0) sD = (mx - mn) * 1.0001f + 1e-6f;  // pad vs fp rounding
    }
    if (tid == 0) scnt = 0;

    // --- X row load + in-block Xmax_b ---
    const float4 xv = ((const float4*)X)[b * (K_DIM / 4) + tid];
    *(float4*)&sX[tid * 4] = xv;     // staged for the (never-taken) fallback
    float m = fmaxf(fmaxf(xv.x, xv.y), fmaxf(xv.z, xv.w));
#pragma unroll
    for (int off = 32; off > 0; off >>= 1)
        m = fmaxf(m, __shfl_down(m, off, 64));
    if ((tid & 63) == 0) sXm[tid >> 6] = m;
    __syncthreads();

    const float xm = fmaxf(fmaxf(sXm[0], sXm[1]), fmaxf(sXm[2], sXm[3]));
    const float thr = xm - sD;

    // --- candidate list ---
    const float xa[4] = {xv.x, xv.y, xv.z, xv.w};
#pragma unroll
    for (int c = 0; c < 4; c++) {
        if (xa[c] > thr) {
            int p = atomicAdd(&scnt, 1);
            if (p < CAP) { sidx[p] = tid * 4 + c; sval[p] = xa[c]; }
        }
    }
    __syncthreads();
    const int n = scnt;

    // --- emit: gather candidate columns of row-major W (L3-resident) ---
    float4 acc = {-3.0e38f, -3.0e38f, -3.0e38f, -3.0e38f};
    const int j0 = tid * 4;
    if (n <= CAP) {
        for (int c = 0; c < n; c++) {
            const int k = sidx[c];
            const float xk = sval[c];
            const float* col = W + k;                  // W[j][k] = W[j*K + k]
            acc.x = fmaxf(acc.x, xk + col[(size_t)(j0 + 0) * K_DIM]);
            acc.y = fmaxf(acc.y, xk + col[(size_t)(j0 + 1) * K_DIM]);
            acc.z = fmaxf(acc.z, xk + col[(size_t)(j0 + 2) * K_DIM]);
            acc.w = fmaxf(acc.w, xk + col[(size_t)(j0 + 3) * K_DIM]);
        }
    } else {
        // overflow fallback (prob ~0): exact full scan; each thread streams
        // its 4 output rows of W with float4, X from LDS.
        float ar[4];
#pragma unroll
        for (int r = 0; r < 4; r++) {
            const float4* row = (const float4*)(W + (size_t)(j0 + r) * K_DIM);
            float a = -3.0e38f;
            for (int k4 = 0; k4 < K_DIM / 4; k4++) {
                float4 w = row[k4];
                a = fmaxf(a, fmaxf(fmaxf(sX[k4 * 4 + 0] + w.x,
                                         sX[k4 * 4 + 1] + w.y),
                                   fmaxf(sX[k4 * 4 + 2] + w.z,
                                         sX[k4 * 4 + 3] + w.w)));
            }
            ar[r] = a;
        }
        acc = make_float4(ar[0], ar[1], ar[2], ar[3]);
    }
    ((float4*)out)[b * (N_DIM / 4) + tid] = acc;
}

extern "C" void kernel_launch(void* const* d_in, const int* in_sizes, int n_in,
                              void* d_out, int out_size, void* d_ws, size_t ws_size,
                              hipStream_t stream) {
    const float* X = (const float*)d_in[0];   // [512][1024]
    const float* W = (const float*)d_in[1];   // [1024][1024]
    float* out = (float*)d_out;               // [512][1024]

    char* ws = (char*)d_ws;
    float* tmax = (float*)(ws + OFF_TMAX);
    float* tmin = (float*)(ws + OFF_TMIN);

    wstats<<<NSTAT, 256, 0, stream>>>(W, tmax, tmin);
    emit_pruned<<<M_DIM, 256, 0, stream>>>(X, W, tmax, tmin, out);
}

// Round 2
// 63.363 us; speedup vs baseline: 1.1333x; 1.1333x over previous
//
#include <hip/hip_runtime.h>
#include <stdint.h>

// Tropical (max-plus) matmul: Y[b][j] = max_k X[b][k] + W[j][k]
// M=512, N=1024, K=1024, fp32 in/out.
//
// Exact candidate pruning: with any D >= max_j (max_k W[j,k] - min_k W[j,k]),
// k with X[b,k] <= Xmax_b - D loses to k* = argmax X[b,:] for every j.
// Global spread D'' = max(W) - min(W) >= that bound (still exact; ~1.4
// candidates/row at W = randn*0.02). CAP overflow -> coalesced full-scan
// fallback keeps the kernel exact for ANY input.
//
// R18 (vs R16 @63.4us, after R17's column-gather regressed to 71.8us):
//   - KEEP the Wt transpose: candidate rows of Wt are coalesced float4
//     reads (R17's direct column gather = 64 lanes x 4KB stride = ~45MB of
//     scattered 64B-line traffic; the 8MB coalesced transpose round-trip
//     is strictly cheaper).
//   - K1 drops the 512 Xmax blocks (grid 768 -> 256): Xmax_b is computed
//     inside K2 from the X row it already loads (wave butterfly + LDS hop).

#define M_DIM 512
#define N_DIM 1024
#define K_DIM 1024
#define CAP 128

// ws layout: Wt 4MB | tmax 1KB | tmin 1KB
#define OFF_WT    0
#define OFF_TMAX  (4u * 1024u * 1024u)
#define OFF_TMIN  (OFF_TMAX + 1024u)

// ---- K1: transpose 64x64 W-tile + tile min/max (256 blocks) ----
__global__ __launch_bounds__(256)
void prep(const float* __restrict__ W, float* __restrict__ Wt,
          float* __restrict__ tmax, float* __restrict__ tmin) {
    __shared__ float L[64][65];     // +1 pad
    __shared__ float smx[4][64];
    __shared__ float smn[4][64];

    const int tid = threadIdx.x;
    const int bx = blockIdx.x;
    const int kt = bx & 15;
    const int jt = bx >> 4;
    const int k0 = kt * 64, j0 = jt * 64;

    {   // load: j-row r, 16 k's per thread
        const int r = tid >> 2, q = tid & 3;
        const float* g = &W[(size_t)(j0 + r) * K_DIM + k0 + q * 16];
#pragma unroll
        for (int t = 0; t < 4; t++) {
            float4 f = *(const float4*)(g + 4 * t);
            L[r][q * 16 + 4 * t + 0] = f.x;
            L[r][q * 16 + 4 * t + 1] = f.y;
            L[r][q * 16 + 4 * t + 2] = f.z;
            L[r][q * 16 + 4 * t + 3] = f.w;
        }
    }
    __syncthreads();
    {   // write Wt tile: k-row kk, 16 j's per thread
        const int kk = tid >> 2, q = tid & 3;
        float* o = &Wt[(size_t)(k0 + kk) * N_DIM + j0 + q * 16];
#pragma unroll
        for (int t = 0; t < 4; t++) {
            float4 f = {L[q * 16 + 4 * t + 0][kk], L[q * 16 + 4 * t + 1][kk],
                        L[q * 16 + 4 * t + 2][kk], L[q * 16 + 4 * t + 3][kk]};
            *(float4*)(o + 4 * t) = f;
        }
    }
    {   // per-j partial min/max (4 threads/j), then tile-global reduce
        const int jl = tid & 63, seg = tid >> 6;
        float mx = -3.0e38f, mn = 3.0e38f;
#pragma unroll
        for (int i = 0; i < 16; i++) {
            float v = L[jl][seg * 16 + i];
            mx = fmaxf(mx, v);
            mn = fminf(mn, v);
        }
        smx[seg][jl] = mx;
        smn[seg][jl] = mn;
    }
    __syncthreads();
    if (tid < 64) {
        float mx = fmaxf(fmaxf(smx[0][tid], smx[1][tid]), fmaxf(smx[2][tid], smx[3][tid]));
        float mn = fminf(fminf(smn[0][tid], smn[1][tid]), fminf(smn[2][tid], smn[3][tid]));
#pragma unroll
        for (int off = 32; off > 0; off >>= 1) {
            mx = fmaxf(mx, __shfl_down(mx, off, 64));
            mn = fminf(mn, __shfl_down(mn, off, 64));
        }
        if (tid == 0) {
            const int id = jt * 16 + kt;
            tmax[id] = mx;
            tmin[id] = mn;
        }
    }
}

// ---- K2: D (wave-0 butterfly), Xmax_b (in-block), candidates, coalesced emit ----
__global__ __launch_bounds__(256)
void emit_pruned(const float* __restrict__ X, const float* __restrict__ Wt,
                 const float* __restrict__ tmax, const float* __restrict__ tmin,
                 float* __restrict__ out) {
    __shared__ float sD;
    __shared__ float sXm[4];
    __shared__ float sX[K_DIM];      // fallback only (one float4 store/thread)
    __shared__ float sval[CAP];
    __shared__ int sidx[CAP];
    __shared__ int scnt;

    const int tid = threadIdx.x;
    const int b = blockIdx.x;

    // --- D'' = max(W) - min(W) from 256 tile pairs (2 KB), wave-0 butterfly ---
    if (tid < 64) {
        float4 a = ((const float4*)tmax)[tid];
        float4 i = ((const float4*)tmin)[tid];
        float mx = fmaxf(fmaxf(a.x, a.y), fmaxf(a.z, a.w));
        float mn = fminf(fminf(i.x, i.y), fminf(i.z, i.w));
#pragma unroll
        for (int off = 32; off > 0; off >>= 1) {
            mx = fmaxf(mx, __shfl_down(mx, off, 64));
            mn = fminf(mn, __shfl_down(mn, off, 64));
        }
        if (tid == 0) sD = (mx - mn) * 1.0001f + 1e-6f;  // pad vs fp rounding
    }
    if (tid == 0) scnt = 0;

    // --- X row load + in-block Xmax_b (wave butterfly + LDS hop) ---
    const float4 xv = ((const float4*)X)[b * (K_DIM / 4) + tid];
    *(float4*)&sX[tid * 4] = xv;
    float m = fmaxf(fmaxf(xv.x, xv.y), fmaxf(xv.z, xv.w));
#pragma unroll
    for (int off = 32; off > 0; off >>= 1)
        m = fmaxf(m, __shfl_down(m, off, 64));
    if ((tid & 63) == 0) sXm[tid >> 6] = m;
    __syncthreads();

    const float xm = fmaxf(fmaxf(sXm[0], sXm[1]), fmaxf(sXm[2], sXm[3]));
    const float thr = xm - sD;

    // --- candidate list ---
    const float xa[4] = {xv.x, xv.y, xv.z, xv.w};
#pragma unroll
    for (int c = 0; c < 4; c++) {
        if (xa[c] > thr) {
            int p = atomicAdd(&scnt, 1);
            if (p < CAP) { sidx[p] = tid * 4 + c; sval[p] = xa[c]; }
        }
    }
    __syncthreads();
    const int n = scnt;

    // --- emit: coalesced float4 reads of Wt candidate rows ---
    float4 acc = {-3.0e38f, -3.0e38f, -3.0e38f, -3.0e38f};
    if (n <= CAP) {
        for (int c = 0; c < n; c++) {
            const int k = sidx[c];
            const float xk = sval[c];
            const float4 w = ((const float4*)Wt)[k * (N_DIM / 4) + tid];
            acc.x = fmaxf(acc.x, xk + w.x);
            acc.y = fmaxf(acc.y, xk + w.y);
            acc.z = fmaxf(acc.z, xk + w.z);
            acc.w = fmaxf(acc.w, xk + w.w);
        }
    } else {
        // overflow fallback (prob ~0): exact full scan, still coalesced
        for (int k = 0; k < K_DIM; k++) {
            const float xk = sX[k];
            const float4 w = ((const float4*)Wt)[k * (N_DIM / 4) + tid];
            acc.x = fmaxf(acc.x, xk + w.x);
            acc.y = fmaxf(acc.y, xk + w.y);
            acc.z = fmaxf(acc.z, xk + w.z);
            acc.w = fmaxf(acc.w, xk + w.w);
        }
    }
    ((float4*)out)[b * (N_DIM / 4) + tid] = acc;
}

extern "C" void kernel_launch(void* const* d_in, const int* in_sizes, int n_in,
                              void* d_out, int out_size, void* d_ws, size_t ws_size,
                              hipStream_t stream) {
    const float* X = (const float*)d_in[0];   // [512][1024]
    const float* W = (const float*)d_in[1];   // [1024][1024]
    float* out = (float*)d_out;               // [512][1024]

    char* ws = (char*)d_ws;
    float* Wt   = (float*)(ws + OFF_WT);
    float* tmax = (float*)(ws + OFF_TMAX);
    float* tmin = (float*)(ws + OFF_TMIN);

    prep<<<256, 256, 0, stream>>>(W, Wt, tmax, tmin);
    emit_pruned<<<M_DIM, 256, 0, stream>>>(X, Wt, tmax, tmin, out);
}